// Round 1
// baseline (470.617 us; speedup 1.0000x reference)
//
#include <hip/hip_runtime.h>
#include <stdint.h>

#define NN 100000
#define DIN 256
#define TOTELEM (NN*DIN)

// ws float offsets
#define WS_SUMH 0
#define WS_SUMH2 1
#define WS_SQ2 2
#define WS_SK2 3
#define WS_MU 4
#define WS_RS 5
#define WS_SQINV 6
#define WS_OFF 8           // 768 floats
#define WS_KSUM 776        // 256 floats (raw k column sums)
#define WS_KSUMS 1032      // 256 floats (scaled)
#define WS_KVS 2048        // 16384 floats (raw kvs, fp32 atomics)
#define WS_KVST 18432      // 8192 floats = 16384 ushort (kvs^T bf16, swizzled)
#define WS_WT 32768        // 98304 floats = 196608 ushort (W^T bf16 [768][256])

typedef __attribute__((ext_vector_type(8))) short short8;
typedef __attribute__((ext_vector_type(4))) float f32x4;

__device__ __forceinline__ unsigned short f2bf(float f){
  uint32_t x = __float_as_uint(f);
  x = (x + 0x7FFFu + ((x >> 16) & 1u)) >> 16;
  return (unsigned short)x;
}
__device__ __forceinline__ float bf2f(unsigned short u){
  return __uint_as_float(((uint32_t)u) << 16);
}

#define STATB 2048

// K1: global LN stats over h + convert W (transposed) to bf16
__global__ __launch_bounds__(256) void k_stats(const float* __restrict__ h,
    const float* __restrict__ Wq, const float* __restrict__ Wk,
    const float* __restrict__ Wv, float* __restrict__ ws){
  int b = blockIdx.x;
  if (b < STATB){
    int tid = b*256 + threadIdx.x;
    const float4* h4 = (const float4*)h;
    float s = 0.f, s2 = 0.f;
    for (int i = tid; i < TOTELEM/4; i += STATB*256){
      float4 v = h4[i];
      s  += (v.x + v.y) + (v.z + v.w);
      s2 += (v.x*v.x + v.y*v.y) + (v.z*v.z + v.w*v.w);
    }
    #pragma unroll
    for (int o = 32; o; o >>= 1){ s += __shfl_down(s,o); s2 += __shfl_down(s2,o); }
    __shared__ float ls[8];
    int w = threadIdx.x >> 6;
    if ((threadIdx.x & 63) == 0){ ls[w] = s; ls[4+w] = s2; }
    __syncthreads();
    if (threadIdx.x == 0){
      atomicAdd(&ws[WS_SUMH],  ls[0]+ls[1]+ls[2]+ls[3]);
      atomicAdd(&ws[WS_SUMH2], ls[4]+ls[5]+ls[6]+ls[7]);
    }
  } else {
    // W^T bf16: Wt[j][k] = W[k][j],  j in [0,768), k in [0,256)
    int cb = b - STATB;                 // 0..191
    int e = cb*1024 + threadIdx.x*4;    // element in [0, 196608)
    int jg = e >> 8, k0 = e & 255;
    const float* W = (jg < 256) ? Wq : ((jg < 512) ? Wk : Wv);
    int jl = jg & 255;
    alignas(8) unsigned short r[4];
    #pragma unroll
    for (int i = 0; i < 4; i++) r[i] = f2bf(W[(k0+i)*256 + jl]);
    unsigned short* Wt = (unsigned short*)(ws + WS_WT);
    *(uint2*)(Wt + jg*256 + k0) = *(uint2*)r;
  }
}

// K2: finalize LN stats + per-output-column offsets off[j] = b[j] - mu*rs*colsum(W[:,j])
__global__ void k_finalize1(const float* __restrict__ Wq, const float* __restrict__ Wk,
    const float* __restrict__ Wv, const float* __restrict__ bq,
    const float* __restrict__ bk, const float* __restrict__ bv, float* __restrict__ ws){
  int j = threadIdx.x; // 768 threads
  float mu  = ws[WS_SUMH]  * (1.0f/TOTELEM);
  float var = ws[WS_SUMH2] * (1.0f/TOTELEM) - mu*mu;
  float rs  = rsqrtf(var + 1e-5f);
  if (j == 0){ ws[WS_MU] = mu; ws[WS_RS] = rs; }
  const float* W  = (j < 256) ? Wq : ((j < 512) ? Wk : Wv);
  const float* bb = (j < 256) ? bq : ((j < 512) ? bk : bv);
  int jl = j & 255;
  float cs = 0.f;
  for (int k = 0; k < 256; k++) cs += W[k*256 + jl];
  ws[WS_OFF + j] = bb[jl] - mu*rs*cs;
}

// K3: fused QKV GEMM (bf16 MFMA) + all global reductions.
// Block: 256 thr (4 waves, 2x2), 128 rows, 6 col-chunks of 128 over [q|k|v].
// LDS: A tile 64KB (swizzled) | kT 32KB | vT 32KB  = 128KB dynamic.
// q,v stored bf16 into d_out rows (q at +0, v at +512 bytes of each 1KB row).
__global__ __launch_bounds__(256) void k_qkv(const float* __restrict__ h,
    float* __restrict__ ws, char* __restrict__ outb){
  extern __shared__ char smem[];
  char* Alds = smem;               // 65536
  char* kT   = smem + 65536;       // 32768: [128 m][256B l] swizzled
  char* vT   = smem + 98304;       // 32768: [128 d][256B l] swizzled
  const unsigned short* Wt = (const unsigned short*)(ws + WS_WT);
  int tid = threadIdx.x;
  int lane = tid & 63, wid = tid >> 6;
  int l15 = lane & 15, lhi = lane >> 4;
  int wm = wid >> 1, wn = wid & 1;
  long rowbase = (long)blockIdx.x * 128;

  // stage A: h fp32 -> bf16 LDS [128][512B], swizzle byte ^= ((r&7)<<4)
  #pragma unroll
  for (int i = 0; i < 16; i++){
    int u = tid + i*256;
    int r = u >> 5, ks = u & 31;
    long grow = rowbase + r;
    float4 f0 = {0,0,0,0}, f1 = {0,0,0,0};
    if (grow < NN){
      const float4* p = (const float4*)(h + grow*DIN + ks*8);
      f0 = p[0]; f1 = p[1];
    }
    alignas(16) unsigned short q8[8];
    q8[0]=f2bf(f0.x); q8[1]=f2bf(f0.y); q8[2]=f2bf(f0.z); q8[3]=f2bf(f0.w);
    q8[4]=f2bf(f1.x); q8[5]=f2bf(f1.y); q8[6]=f2bf(f1.z); q8[7]=f2bf(f1.w);
    int byte = (r*512 + ks*16) ^ ((r&7)<<4);
    *(uint4*)(Alds + byte) = *(uint4*)q8;
  }
  __syncthreads();

  float rs = ws[WS_RS];
  float sq2 = 0.f, sk2 = 0.f;

  const int order[6] = {0,1,2,4,3,5};  // q,q,k01,v01,k23,v23
  #pragma unroll
  for (int oc = 0; oc < 6; oc++){
    int c = order[oc];
    int type = (c < 2) ? 0 : ((c < 4) ? 1 : 2);
    f32x4 acc[4][4];
    #pragma unroll
    for (int a = 0; a < 4; a++)
      #pragma unroll
      for (int b2 = 0; b2 < 4; b2++) acc[a][b2] = (f32x4){0.f,0.f,0.f,0.f};

    #pragma unroll
    for (int kstep = 0; kstep < 8; kstep++){
      short8 bf_[4];
      #pragma unroll
      for (int nt = 0; nt < 4; nt++){
        int n = c*128 + wn*64 + nt*16 + l15;
        bf_[nt] = *(const short8*)(Wt + n*256 + kstep*32 + lhi*8);
      }
      short8 af[4];
      #pragma unroll
      for (int mt = 0; mt < 4; mt++){
        int r = wm*64 + mt*16 + l15;
        int byte = (r*512 + kstep*64 + lhi*16) ^ ((r&7)<<4);
        af[mt] = *(const short8*)(Alds + byte);
      }
      #pragma unroll
      for (int mt = 0; mt < 4; mt++)
        #pragma unroll
        for (int nt = 0; nt < 4; nt++)
          acc[mt][nt] = __builtin_amdgcn_mfma_f32_16x16x32_bf16(af[mt], bf_[nt], acc[mt][nt], 0, 0, 0);
    }

    // epilogue
    float kspart[4] = {0.f,0.f,0.f,0.f};
    #pragma unroll
    for (int nt = 0; nt < 4; nt++){
      int col = c*128 + wn*64 + nt*16 + l15;
      float offv = ws[WS_OFF + col];
      #pragma unroll
      for (int mt = 0; mt < 4; mt++){
        #pragma unroll
        for (int jj = 0; jj < 4; jj++){
          int lrow = wm*64 + mt*16 + lhi*4 + jj;
          long grow = rowbase + lrow;
          bool valid = grow < NN;
          float y = rs*acc[mt][nt][jj] + offv;
          float yv = valid ? y : 0.f;
          if (type == 0){
            if (valid) *(unsigned short*)(outb + grow*1024 + col*2) = f2bf(y);
            sq2 += yv*yv;
          } else if (type == 1){
            sk2 += yv*yv;
            kspart[nt] += yv;
            int mloc = col - ((c == 2) ? 256 : 384);
            *(unsigned short*)(kT + ((mloc*256 + lrow*2) ^ ((mloc&7)<<4))) = f2bf(yv);
          } else {
            if (valid) *(unsigned short*)(outb + grow*1024 + 512 + (col-512)*2) = f2bf(y);
            int dloc = col - ((c == 4) ? 512 : 640);
            *(unsigned short*)(vT + ((dloc*256 + lrow*2) ^ ((dloc&7)<<4))) = f2bf(yv);
          }
        }
      }
    }
    if (type == 1){
      #pragma unroll
      for (int nt = 0; nt < 4; nt++){
        float v = kspart[nt];
        v += __shfl_xor(v, 16);
        v += __shfl_xor(v, 32);
        if (lane < 16){
          int col = c*128 + wn*64 + nt*16 + l15;
          atomicAdd(&ws[WS_KSUM + col - 256], v);
        }
      }
    }
    if (type == 2){
      __syncthreads();
      int hpair = (c == 4) ? 0 : 2;
      int hh = wid >> 1;       // head within pair
      int mh = (wid & 1) * 32; // m half
      f32x4 kacc[2][4];
      #pragma unroll
      for (int a = 0; a < 2; a++)
        #pragma unroll
        for (int b2 = 0; b2 < 4; b2++) kacc[a][b2] = (f32x4){0.f,0.f,0.f,0.f};
      #pragma unroll
      for (int ks = 0; ks < 4; ks++){
        short8 ka[2], vb[4];
        #pragma unroll
        for (int mt = 0; mt < 2; mt++){
          int mloc = hh*64 + mh + mt*16 + l15;
          ka[mt] = *(const short8*)(kT + ((mloc*256 + ks*64 + lhi*16) ^ ((mloc&7)<<4)));
        }
        #pragma unroll
        for (int nt = 0; nt < 4; nt++){
          int dloc = hh*64 + nt*16 + l15;
          vb[nt] = *(const short8*)(vT + ((dloc*256 + ks*64 + lhi*16) ^ ((dloc&7)<<4)));
        }
        #pragma unroll
        for (int mt = 0; mt < 2; mt++)
          #pragma unroll
          for (int nt = 0; nt < 4; nt++)
            kacc[mt][nt] = __builtin_amdgcn_mfma_f32_16x16x32_bf16(ka[mt], vb[nt], kacc[mt][nt], 0, 0, 0);
      }
      int hglob = hpair + hh;
      #pragma unroll
      for (int mt = 0; mt < 2; mt++)
        #pragma unroll
        for (int nt = 0; nt < 4; nt++)
          #pragma unroll
          for (int jj = 0; jj < 4; jj++){
            int m64 = mh + mt*16 + lhi*4 + jj;
            int d64 = nt*16 + l15;
            atomicAdd(&ws[WS_KVS + hglob*4096 + m64*64 + d64], kacc[mt][nt][jj]);
          }
      __syncthreads();
    }
  }

  // block-reduce sq2, sk2 -> atomics
  #pragma unroll
  for (int o = 32; o; o >>= 1){ sq2 += __shfl_down(sq2,o); sk2 += __shfl_down(sk2,o); }
  float* red = (float*)smem;  // A region dead now
  if (lane == 0){ red[wid] = sq2; red[4+wid] = sk2; }
  __syncthreads();
  if (tid == 0){
    atomicAdd(&ws[WS_SQ2], red[0]+red[1]+red[2]+red[3]);
    atomicAdd(&ws[WS_SK2], red[4]+red[5]+red[6]+red[7]);
  }
}

// K4: norms; kvs^T scaled -> bf16 (swizzled); ksum scaled
__global__ void k_finalize2(float* __restrict__ ws){
  int t = threadIdx.x; // 256
  float nq = sqrtf(ws[WS_SQ2]);
  float nk = sqrtf(ws[WS_SK2]);
  if (t == 0) ws[WS_SQINV] = 1.0f/nq;
  float ink = 1.0f/nk;
  unsigned short* kvst = (unsigned short*)(ws + WS_KVST);
  for (int i = t; i < 16384; i += 256){
    int hh = i >> 12;
    int d = (i >> 6) & 63;
    int m = i & 63;
    float val = ws[WS_KVS + hh*4096 + m*64 + d] * ink;
    kvst[i ^ ((d&7)<<3)] = f2bf(val);   // kvst[h][d][m], swizzled on bit3
  }
  for (int i = t; i < 256; i += 256)
    ws[WS_KSUMS + i] = ws[WS_KSUM + i] * ink;
}

// K5: out = (Sq * q@kvs_s + N*v) / (Sq * q.ksum_s + N), in-place over d_out rows.
// Block: 256 thr (4 waves = 4 heads), 64 rows. LDS 67584B dynamic.
__global__ __launch_bounds__(256) void k_out(float* __restrict__ ws, char* __restrict__ outb){
  extern __shared__ char smem[];
  char* qlds = smem;                       // 32768, swizzled
  char* Blds = smem + 32768;               // 32768: kvsT, later reused for v
  float* denl = (float*)(smem + 65536);    // 64*4 floats
  float* ksl  = (float*)(smem + 66560);    // 256 floats
  int tid = threadIdx.x;
  int lane = tid & 63, wid = tid >> 6;
  int l15 = lane & 15, lhi = lane >> 4;
  long rowbase = (long)blockIdx.x * 64;

  // stage q (bf16 from d_out rows, swizzled)
  #pragma unroll
  for (int i = 0; i < 8; i++){
    int u = tid + i*256;
    int r = u >> 5, ks = u & 31;
    long grow = rowbase + r;
    uint4 val = {0,0,0,0};
    if (grow < NN) val = *(const uint4*)(outb + grow*1024 + ks*16);
    *(uint4*)(qlds + ((r*512 + ks*16) ^ ((r&7)<<4))) = val;
  }
  // stage kvsT (verbatim copy; pre-swizzled in ws)
  {
    const uint4* src = (const uint4*)(ws + WS_KVST);
    uint4* dst = (uint4*)Blds;
    #pragma unroll
    for (int i = 0; i < 8; i++) dst[tid + i*256] = src[tid + i*256];
  }
  ksl[tid] = ws[WS_KSUMS + tid];
  __syncthreads();

  float Sq = ws[WS_SQINV];
  f32x4 acc[4][4];
  #pragma unroll
  for (int a = 0; a < 4; a++)
    #pragma unroll
    for (int b2 = 0; b2 < 4; b2++) acc[a][b2] = (f32x4){0.f,0.f,0.f,0.f};

  #pragma unroll
  for (int ks2 = 0; ks2 < 2; ks2++){
    short8 af[4], bf_[4];
    #pragma unroll
    for (int mt = 0; mt < 4; mt++){
      int r = mt*16 + l15;
      af[mt] = *(const short8*)(qlds + ((r*512 + wid*128 + ks2*64 + lhi*16) ^ ((r&7)<<4)));
    }
    #pragma unroll
    for (int dt = 0; dt < 4; dt++){
      int d = dt*16 + l15;
      int idx = (wid*4096 + d*64 + ks2*32 + lhi*8) ^ ((d&7)<<3);
      bf_[dt] = *(const short8*)(Blds + idx*2);
    }
    #pragma unroll
    for (int mt = 0; mt < 4; mt++)
      #pragma unroll
      for (int dt = 0; dt < 4; dt++)
        acc[mt][dt] = __builtin_amdgcn_mfma_f32_16x16x32_bf16(af[mt], bf_[dt], acc[mt][dt], 0, 0, 0);
  }

  // den[row][h] = Sq * dot(q_row_h, ksum_s_h) + N
  {
    int r = tid & 63, h2 = tid >> 6;
    float dot = 0.f;
    #pragma unroll 8
    for (int m = 0; m < 64; m++){
      unsigned short qv = *(const unsigned short*)(qlds + ((r*512 + (h2*64+m)*2) ^ ((r&7)<<4)));
      dot += bf2f(qv) * ksl[h2*64 + m];
    }
    denl[r*4 + h2] = Sq*dot + (float)NN;
  }
  __syncthreads();

  // stage v into Blds (unswizzled)
  #pragma unroll
  for (int i = 0; i < 8; i++){
    int u = tid + i*256;
    int r = u >> 5, ks = u & 31;
    long grow = rowbase + r;
    uint4 val = {0,0,0,0};
    if (grow < NN) val = *(const uint4*)(outb + grow*1024 + 512 + ks*16);
    *(uint4*)(Blds + r*512 + ks*16) = val;
  }
  __syncthreads();

  float Nf = (float)NN;
  #pragma unroll
  for (int mt = 0; mt < 4; mt++)
    #pragma unroll
    for (int dt = 0; dt < 4; dt++)
      #pragma unroll
      for (int jj = 0; jj < 4; jj++){
        int r = mt*16 + lhi*4 + jj;
        int j = wid*64 + dt*16 + l15;
        long grow = rowbase + r;
        if (grow < NN){
          float v = bf2f(*(const unsigned short*)(Blds + r*512 + j*2));
          float num = Sq*acc[mt][dt][jj] + Nf*v;
          *(float*)(outb + grow*1024 + j*4) = num / denl[r*4 + wid];
        }
      }
}

extern "C" void kernel_launch(void* const* d_in, const int* in_sizes, int n_in,
                              void* d_out, int out_size, void* d_ws, size_t ws_size,
                              hipStream_t stream) {
  const float* h  = (const float*)d_in[0];
  const float* Wq = (const float*)d_in[1];
  const float* bq = (const float*)d_in[2];
  const float* Wk = (const float*)d_in[3];
  const float* bk = (const float*)d_in[4];
  const float* Wv = (const float*)d_in[5];
  const float* bv = (const float*)d_in[6];
  float* ws = (float*)d_ws;
  char* outb = (char*)d_out;

  // zero accumulators (sums, off, ksum, kvs)
  hipMemsetAsync(d_ws, 0, 18432*4, stream);

  k_stats<<<STATB + 192, 256, 0, stream>>>(h, Wq, Wk, Wv, ws);
  k_finalize1<<<1, 768, 0, stream>>>(Wq, Wk, Wv, bq, bk, bv, ws);

  hipFuncSetAttribute(reinterpret_cast<const void*>(k_qkv),
                      hipFuncAttributeMaxDynamicSharedMemorySize, 131072);
  k_qkv<<<(NN + 127)/128, 256, 131072, stream>>>(h, ws, outb);

  k_finalize2<<<1, 256, 0, stream>>>(ws);

  hipFuncSetAttribute(reinterpret_cast<const void*>(k_out),
                      hipFuncAttributeMaxDynamicSharedMemorySize, 67584);
  k_out<<<(NN + 63)/64, 256, 67584, stream>>>(ws, outb);
}

// Round 2
// 404.372 us; speedup vs baseline: 1.1638x; 1.1638x over previous
//
#include <hip/hip_runtime.h>
#include <stdint.h>

#define NN 100000
#define DIN 256
#define TOTELEM (NN*DIN)

// ws float offsets
#define WS_SUMS 0      // [8][4]: sumh, sumh2, s2q, s2k
#define WS_CS8  32     // [4][768] raw colsums (q|k|v)
#define WS_KV   3104   // [4][64][64] raw k^T v
#define WS_OFFQ 19488  // [256]
#define WS_OFFK 19744  // [256]
#define WS_OFFV 20000  // [256]
#define WS_SC   20256  // 0=mu 1=rs 2=Sq(1/nq)
#define WS_KSB  20264  // bf16[256] scaled ksum (128 floats)
#define WS_KVST 20480  // ushort[16384] scaled kvs^T bf16 swizzled
#define WS_CSW  28672  // [768] W colsums
#define WS_WT   29440  // ushort[196608] W^T bf16 [768][256]

typedef __attribute__((ext_vector_type(8))) short short8;
typedef __attribute__((ext_vector_type(4))) float f32x4;

__device__ __forceinline__ unsigned short f2bf(float f){
  uint32_t x = __float_as_uint(f);
  x = (x + 0x7FFFu + ((x >> 16) & 1u)) >> 16;
  return (unsigned short)x;
}
__device__ __forceinline__ float bf2f(unsigned short u){
  return __uint_as_float(((uint32_t)u) << 16);
}
// manual OCP e4m3fn encode (RNE, saturate to 448) / decode
__device__ __forceinline__ unsigned char f2e4m3(float f){
  uint32_t u = __float_as_uint(f);
  unsigned char s = (unsigned char)((u >> 24) & 0x80u);
  uint32_t au = u & 0x7FFFFFFFu;
  float a = __uint_as_float(au);
  if (a >= 448.f) return s | 0x7E;
  if (a < 0.015625f){
    int q = (int)rintf(a * 512.f);
    return s | (unsigned char)q;
  }
  uint32_t u2 = au + 0x7FFFFu + ((au >> 20) & 1u);
  int eb = (int)(u2 >> 23) - 120;
  uint32_t m = (u2 >> 20) & 7u;
  return s | (unsigned char)(eb << 3) | (unsigned char)m;
}
__device__ __forceinline__ float e4m3f(unsigned char b){
  uint32_t s = ((uint32_t)(b & 0x80u)) << 24;
  uint32_t em = b & 0x7Fu;
  float v;
  if ((em >> 3) == 0) v = (float)em * 0.001953125f;
  else v = __uint_as_float((((em >> 3) + 120u) << 23) | ((em & 7u) << 20));
  return __uint_as_float(__float_as_uint(v) | s);
}

// K0: W^T bf16 convert (coalesced, LDS transpose) + W column sums
__global__ __launch_bounds__(256) void k_prep(const float* __restrict__ Wq,
    const float* __restrict__ Wk, const float* __restrict__ Wv, float* __restrict__ ws){
  __shared__ char lds[16384];
  int tid = threadIdx.x;
  int bm = blockIdx.x >> 4;
  int slab = blockIdx.x & 15;
  const float* W = (bm == 0) ? Wq : ((bm == 1) ? Wk : Wv);
  int kbase = slab * 16;
  #pragma unroll
  for (int i = 0; i < 4; i++){
    int idx = tid + i*256;
    int r = idx >> 6, g = idx & 63;
    float4 v = *(const float4*)(W + (kbase + r)*256 + g*4);
    *(float4*)(lds + ((r*1024 + g*16) ^ ((r&7)<<4))) = v;
  }
  __syncthreads();
  int j = tid;
  alignas(16) unsigned short us[16];
  float cs = 0.f;
  #pragma unroll
  for (int r = 0; r < 16; r++){
    float f = *(const float*)(lds + ((r*1024 + j*4) ^ ((r&7)<<4)));
    cs += f;
    us[r] = f2bf(f);
  }
  unsigned short* Wt = (unsigned short*)(ws + WS_WT);
  *(uint4*)(Wt + (bm*256 + j)*256 + kbase)     = *(uint4*)us;
  *(uint4*)(Wt + (bm*256 + j)*256 + kbase + 8) = *(uint4*)(us + 8);
  atomicAdd(&ws[WS_CSW + bm*256 + j], cs);
}

// K2: fused h-stats + raw QKV GEMM + raw colsums/S2; writes q fp8|k fp8|v bf16
__global__ __launch_bounds__(256, 3) void k_qkv(const float* __restrict__ h,
    float* __restrict__ ws, char* __restrict__ outb){
  extern __shared__ char smem[];
  char* Alds = smem;            // 32768: [64][512B] bf16 swizzled
  char* ost  = smem + 32768;    // 16384 store-stage
  const unsigned short* Wt = (const unsigned short*)(ws + WS_WT);
  int tid = threadIdx.x;
  int lane = tid & 63, wid = tid >> 6;
  int l15 = lane & 15, lhi = lane >> 4;
  long rowbase = (long)blockIdx.x * 64;

  float s = 0.f, s2 = 0.f;
  #pragma unroll
  for (int i = 0; i < 8; i++){
    int u = tid + i*256;
    int r = u >> 5, ks = u & 31;
    long grow = rowbase + r;
    float4 f0 = {0,0,0,0}, f1 = {0,0,0,0};
    if (grow < NN){
      const float4* p = (const float4*)(h + grow*DIN + ks*8);
      f0 = p[0]; f1 = p[1];
    }
    s  += (f0.x+f0.y)+(f0.z+f0.w) + (f1.x+f1.y)+(f1.z+f1.w);
    s2 += (f0.x*f0.x+f0.y*f0.y)+(f0.z*f0.z+f0.w*f0.w)
        + (f1.x*f1.x+f1.y*f1.y)+(f1.z*f1.z+f1.w*f1.w);
    alignas(16) unsigned short q8[8];
    q8[0]=f2bf(f0.x); q8[1]=f2bf(f0.y); q8[2]=f2bf(f0.z); q8[3]=f2bf(f0.w);
    q8[4]=f2bf(f1.x); q8[5]=f2bf(f1.y); q8[6]=f2bf(f1.z); q8[7]=f2bf(f1.w);
    *(uint4*)(Alds + ((r*512 + ks*16) ^ ((r&7)<<4))) = *(uint4*)q8;
  }
  #pragma unroll
  for (int o = 32; o; o >>= 1){ s += __shfl_down(s,o); s2 += __shfl_down(s2,o); }
  if (lane == 0){
    atomicAdd(&ws[WS_SUMS + (blockIdx.x&7)*4 + 0], s);
    atomicAdd(&ws[WS_SUMS + (blockIdx.x&7)*4 + 1], s2);
  }
  __syncthreads();

  float s2q = 0.f, s2k = 0.f;
  #pragma unroll 1
  for (int c = 0; c < 6; c++){
    f32x4 acc[4][2];
    #pragma unroll
    for (int a = 0; a < 4; a++)
      #pragma unroll
      for (int b = 0; b < 2; b++) acc[a][b] = (f32x4){0.f,0.f,0.f,0.f};
    #pragma unroll
    for (int kstep = 0; kstep < 8; kstep++){
      short8 bf_[2], af[4];
      #pragma unroll
      for (int nt = 0; nt < 2; nt++){
        int n = c*128 + wid*32 + nt*16 + l15;
        bf_[nt] = *(const short8*)(Wt + n*256 + kstep*32 + lhi*8);
      }
      #pragma unroll
      for (int mt = 0; mt < 4; mt++){
        int r = mt*16 + l15;
        af[mt] = *(const short8*)(Alds + ((r*512 + kstep*64 + lhi*16) ^ ((r&7)<<4)));
      }
      #pragma unroll
      for (int mt = 0; mt < 4; mt++)
        #pragma unroll
        for (int nt = 0; nt < 2; nt++)
          acc[mt][nt] = __builtin_amdgcn_mfma_f32_16x16x32_bf16(af[mt], bf_[nt], acc[mt][nt], 0, 0, 0);
    }
    // raw column sums (1 atomic per col per block)
    #pragma unroll
    for (int nt = 0; nt < 2; nt++){
      float p = 0.f;
      #pragma unroll
      for (int mt = 0; mt < 4; mt++)
        #pragma unroll
        for (int jj = 0; jj < 4; jj++) p += acc[mt][nt][jj];
      p += __shfl_xor(p, 16); p += __shfl_xor(p, 32);
      if (lane < 16)
        atomicAdd(&ws[WS_CS8 + (blockIdx.x&3)*768 + c*128 + wid*32 + nt*16 + l15], p);
    }
    if (c < 4){
      float t = 0.f;
      #pragma unroll
      for (int mt = 0; mt < 4; mt++)
        #pragma unroll
        for (int nt = 0; nt < 2; nt++)
          #pragma unroll
          for (int jj = 0; jj < 4; jj++){ float a = acc[mt][nt][jj]; t += a*a; }
      if (c < 2) s2q += t; else s2k += t;
    }
    __syncthreads();
    if (c < 4){
      #pragma unroll
      for (int mt = 0; mt < 4; mt++)
        #pragma unroll
        for (int nt = 0; nt < 2; nt++)
          #pragma unroll
          for (int jj = 0; jj < 4; jj++){
            int row = mt*16 + lhi*4 + jj;
            int colc = wid*32 + nt*16 + l15;
            ost[(row*128 + colc) ^ (((row>>2)&7)<<4)] = f2e4m3(acc[mt][nt][jj]);
          }
      __syncthreads();
      #pragma unroll
      for (int i = 0; i < 2; i++){
        int idx = tid + i*256;
        int row = idx >> 3, in16 = (idx & 7)*16;
        long grow = rowbase + row;
        if (grow < NN){
          uint4 val = *(uint4*)(ost + ((row*128 + in16) ^ (((row>>2)&7)<<4)));
          *(uint4*)(outb + grow*1024 + c*128 + in16) = val;
        }
      }
    } else {
      #pragma unroll
      for (int mt = 0; mt < 4; mt++)
        #pragma unroll
        for (int nt = 0; nt < 2; nt++)
          #pragma unroll
          for (int jj = 0; jj < 4; jj++){
            int row = mt*16 + lhi*4 + jj;
            int colc = wid*32 + nt*16 + l15;
            *(unsigned short*)(ost + ((row*256 + colc*2) ^ (((row>>2)&7)<<4))) = f2bf(acc[mt][nt][jj]);
          }
      __syncthreads();
      #pragma unroll
      for (int i = 0; i < 4; i++){
        int idx = tid + i*256;
        int row = idx >> 4, in16 = (idx & 15)*16;
        long grow = rowbase + row;
        if (grow < NN){
          uint4 val = *(uint4*)(ost + ((row*256 + in16) ^ (((row>>2)&7)<<4)));
          *(uint4*)(outb + grow*1024 + 512 + (c-4)*256 + in16) = val;
        }
      }
    }
  }
  #pragma unroll
  for (int o = 32; o; o >>= 1){ s2q += __shfl_down(s2q,o); s2k += __shfl_down(s2k,o); }
  if (lane == 0){
    atomicAdd(&ws[WS_SUMS + (blockIdx.x&7)*4 + 2], s2q);
    atomicAdd(&ws[WS_SUMS + (blockIdx.x&7)*4 + 3], s2k);
  }
}

// K3: raw KV[h][m][d] = sum_l k[l,m] v[l,d] via LDS transpose + MFMA, atomics to ws
#define KVGRID 512
__global__ __launch_bounds__(256, 2) void k_kv(const char* __restrict__ outb,
                                               float* __restrict__ ws){
  extern __shared__ char smem[];
  char* kRM = smem;            // 8192: [32][256B fp8] swz
  char* vRM = smem + 8192;     // 16384: [32][512B bf16] swz
  char* kT  = smem + 24576;    // 16384: [256][64B bf16] swz
  char* vT  = smem + 40960;    // 16384
  int tid = threadIdx.x;
  int lane = tid & 63, wid = tid >> 6;
  int l15 = lane & 15, lhi = lane >> 4;
  f32x4 acc[4][4];
  #pragma unroll
  for (int a = 0; a < 4; a++)
    #pragma unroll
    for (int b = 0; b < 4; b++) acc[a][b] = (f32x4){0.f,0.f,0.f,0.f};

  for (int t = blockIdx.x; t < (NN + 31)/32; t += KVGRID){
    long rowbase = (long)t * 32;
    __syncthreads();
    #pragma unroll
    for (int i = 0; i < 2; i++){
      int idx = tid + i*256;
      int r = idx >> 4, g = idx & 15;
      long grow = rowbase + r;
      uint4 val = {0,0,0,0};
      if (grow < NN) val = *(const uint4*)(outb + grow*1024 + 256 + g*16);
      *(uint4*)(kRM + ((r*256 + g*16) ^ ((r&7)<<4))) = val;
    }
    #pragma unroll
    for (int i = 0; i < 4; i++){
      int idx = tid + i*256;
      int r = idx >> 5, g = idx & 31;
      long grow = rowbase + r;
      uint4 val = {0,0,0,0};
      if (grow < NN) val = *(const uint4*)(outb + grow*1024 + 512 + g*16);
      *(uint4*)(vRM + ((r*512 + g*16) ^ ((r&7)<<4))) = val;
    }
    __syncthreads();
    {
      int col = tid;  // 256 columns
      alignas(16) unsigned short tmp[32];
      #pragma unroll
      for (int r = 0; r < 32; r++){
        unsigned char b = *(const unsigned char*)(kRM + ((r*256 + col) ^ ((r&7)<<4)));
        tmp[r] = f2bf(e4m3f(b));
      }
      #pragma unroll
      for (int sg = 0; sg < 4; sg++)
        *(uint4*)(kT + ((col*64 + sg*16) ^ ((col&7)<<4))) = *(uint4*)(tmp + sg*8);
      #pragma unroll
      for (int r = 0; r < 32; r++)
        tmp[r] = *(const unsigned short*)(vRM + ((r*512 + col*2) ^ ((r&7)<<4)));
      #pragma unroll
      for (int sg = 0; sg < 4; sg++)
        *(uint4*)(vT + ((col*64 + sg*16) ^ ((col&7)<<4))) = *(uint4*)(tmp + sg*8);
    }
    __syncthreads();
    short8 af[4], bf_[4];
    #pragma unroll
    for (int mt = 0; mt < 4; mt++){
      int m = wid*64 + mt*16 + l15;
      af[mt] = *(const short8*)(kT + ((m*64 + lhi*16) ^ ((m&7)<<4)));
    }
    #pragma unroll
    for (int nt = 0; nt < 4; nt++){
      int d = wid*64 + nt*16 + l15;
      bf_[nt] = *(const short8*)(vT + ((d*64 + lhi*16) ^ ((d&7)<<4)));
    }
    #pragma unroll
    for (int mt = 0; mt < 4; mt++)
      #pragma unroll
      for (int nt = 0; nt < 4; nt++)
        acc[mt][nt] = __builtin_amdgcn_mfma_f32_16x16x32_bf16(af[mt], bf_[nt], acc[mt][nt], 0, 0, 0);
  }
  #pragma unroll
  for (int mt = 0; mt < 4; mt++)
    #pragma unroll
    for (int nt = 0; nt < 4; nt++)
      #pragma unroll
      for (int jj = 0; jj < 4; jj++){
        int m = mt*16 + lhi*4 + jj, d = nt*16 + l15;
        atomicAdd(&ws[WS_KV + wid*4096 + m*64 + d], acc[mt][nt][jj]);
      }
}

// K4: finalize stats; offsets; sq2/sk2 via raw expansion; scaled ksum bf16; scaled kvs^T bf16
__global__ void k_fin(const float* __restrict__ bq, const float* __restrict__ bk,
                      const float* __restrict__ bv, float* __restrict__ ws){
  __shared__ float red[256];
  __shared__ float cskS[256], csvS[256], okS[256], ovS[256];
  int tid = threadIdx.x;
  float SUMH = 0.f, SUMH2 = 0.f, S2Q = 0.f, S2K = 0.f;
  #pragma unroll
  for (int i = 0; i < 8; i++){
    SUMH  += ws[WS_SUMS + i*4 + 0];
    SUMH2 += ws[WS_SUMS + i*4 + 1];
    S2Q   += ws[WS_SUMS + i*4 + 2];
    S2K   += ws[WS_SUMS + i*4 + 3];
  }
  float mu  = SUMH  * (1.0f/(float)TOTELEM);
  float var = SUMH2 * (1.0f/(float)TOTELEM) - mu*mu;
  float rs  = rsqrtf(var + 1e-5f);
  int j = tid;
  float csq = 0.f, csk = 0.f, csv = 0.f;
  #pragma unroll
  for (int cp = 0; cp < 4; cp++){
    csq += ws[WS_CS8 + cp*768 + j];
    csk += ws[WS_CS8 + cp*768 + 256 + j];
    csv += ws[WS_CS8 + cp*768 + 512 + j];
  }
  float oq = bq[j] - mu*rs*ws[WS_CSW + j];
  float ok = bk[j] - mu*rs*ws[WS_CSW + 256 + j];
  float ov = bv[j] - mu*rs*ws[WS_CSW + 512 + j];
  ws[WS_OFFQ + j] = oq; ws[WS_OFFK + j] = ok; ws[WS_OFFV + j] = ov;
  cskS[j] = csk; csvS[j] = csv; okS[j] = ok; ovS[j] = ov;
  float Nf = (float)NN;
  red[tid] = 2.f*rs*oq*csq + Nf*oq*oq;
  for (int o = 128; o; o >>= 1){ __syncthreads(); if (tid < o) red[tid] += red[tid+o]; }
  __syncthreads();
  float sq2 = rs*rs*S2Q + red[0];
  __syncthreads();
  red[tid] = 2.f*rs*ok*csk + Nf*ok*ok;
  for (int o = 128; o; o >>= 1){ __syncthreads(); if (tid < o) red[tid] += red[tid+o]; }
  __syncthreads();
  float sk2 = rs*rs*S2K + red[0];
  float nq = sqrtf(sq2), nk = sqrtf(sk2);
  if (tid == 0){ ws[WS_SC+0] = mu; ws[WS_SC+1] = rs; ws[WS_SC+2] = 1.f/nq; }
  float ink = 1.f/nk;
  ((unsigned short*)(ws + WS_KSB))[j] = f2bf((rs*csk + Nf*ok) * ink);
  __syncthreads();
  float rs2 = rs*rs;
  unsigned short* kvst = (unsigned short*)(ws + WS_KVST);
  for (int i = tid; i < 16384; i += 256){
    int hh = i >> 12, d = (i >> 6) & 63, m = i & 63;
    int gm = hh*64 + m, gd = hh*64 + d;
    float raw = ws[WS_KV + hh*4096 + m*64 + d];
    float val = (rs2*raw + rs*okS[gm]*csvS[gd] + rs*ovS[gd]*cskS[gm] + Nf*okS[gm]*ovS[gd]) * ink;
    kvst[i ^ ((d&7)<<3)] = f2bf(val);
  }
}

// K5: out = (Sq*(q_s@kvs_s) + N*v_s) / (Sq*(q_s.ksum_s) + N), den via extra MFMA col
__global__ __launch_bounds__(256, 2) void k_out(const float* __restrict__ ws,
                                                char* __restrict__ outb){
  extern __shared__ char smem[];
  char* qlds  = smem;              // 32768: [64][512B] bf16 swz
  char* Blds  = smem + 32768;      // 32768: kvst, then v_s
  char* ksbf  = smem + 65536;      // 512
  float* offqL = (float*)(smem + 66048);  // 256 f
  float* offvL = (float*)(smem + 67072);  // 256 f
  int tid = threadIdx.x;
  int lane = tid & 63, wid = tid >> 6;
  int l15 = lane & 15, lhi = lane >> 4;
  long rowbase = (long)blockIdx.x * 64;

  {
    const uint4* src = (const uint4*)(ws + WS_KVST);
    uint4* dst = (uint4*)Blds;
    #pragma unroll
    for (int i = 0; i < 8; i++) dst[tid + i*256] = src[tid + i*256];
  }
  offqL[tid] = ws[WS_OFFQ + tid];
  offvL[tid] = ws[WS_OFFV + tid];
  ((unsigned short*)ksbf)[tid] = ((const unsigned short*)(ws + WS_KSB))[tid];
  float rs = ws[WS_SC + 1];
  float Sq = ws[WS_SC + 2];
  __syncthreads();

  #pragma unroll
  for (int i = 0; i < 4; i++){
    int idx = tid + i*256;
    int r = idx >> 4, g = idx & 15;
    long grow = rowbase + r;
    uint4 raw = {0,0,0,0};
    if (grow < NN) raw = *(const uint4*)(outb + grow*1024 + g*16);
    const unsigned char* pb = (const unsigned char*)&raw;
    alignas(16) unsigned short us[16];
    #pragma unroll
    for (int jx = 0; jx < 16; jx++)
      us[jx] = f2bf(rs * e4m3f(pb[jx]) + offqL[g*16 + jx]);
    int base = r*512 + g*32;
    *(uint4*)(qlds + ((base)      ^ ((r&7)<<4))) = *(uint4*)us;
    *(uint4*)(qlds + ((base + 16) ^ ((r&7)<<4))) = *(uint4*)(us + 8);
  }
  __syncthreads();

  f32x4 acc[4][4]; f32x4 accd[4];
  #pragma unroll
  for (int a = 0; a < 4; a++){
    accd[a] = (f32x4){0.f,0.f,0.f,0.f};
    #pragma unroll
    for (int b = 0; b < 4; b++) acc[a][b] = (f32x4){0.f,0.f,0.f,0.f};
  }
  #pragma unroll
  for (int ks2 = 0; ks2 < 2; ks2++){
    short8 af[4], bf_[4], bden;
    #pragma unroll
    for (int mt = 0; mt < 4; mt++){
      int r = mt*16 + l15;
      af[mt] = *(const short8*)(qlds + ((r*512 + wid*128 + ks2*64 + lhi*16) ^ ((r&7)<<4)));
    }
    #pragma unroll
    for (int dt = 0; dt < 4; dt++){
      int d = dt*16 + l15;
      int idx = (wid*4096 + d*64 + ks2*32 + lhi*8) ^ ((d&7)<<3);
      bf_[dt] = *(const short8*)(Blds + idx*2);
    }
    if (l15 == 0) bden = *(const short8*)(ksbf + wid*128 + ks2*64 + lhi*16);
    else bden = (short8){0,0,0,0,0,0,0,0};
    #pragma unroll
    for (int mt = 0; mt < 4; mt++)
      #pragma unroll
      for (int dt = 0; dt < 4; dt++)
        acc[mt][dt] = __builtin_amdgcn_mfma_f32_16x16x32_bf16(af[mt], bf_[dt], acc[mt][dt], 0, 0, 0);
    #pragma unroll
    for (int mt = 0; mt < 4; mt++)
      accd[mt] = __builtin_amdgcn_mfma_f32_16x16x32_bf16(af[mt], bden, accd[mt], 0, 0, 0);
  }
  __syncthreads();

  #pragma unroll
  for (int i = 0; i < 8; i++){
    int idx = tid + i*256;
    int r = idx >> 5, g = idx & 31;
    long grow = rowbase + r;
    uint4 raw = {0,0,0,0};
    if (grow < NN) raw = *(const uint4*)(outb + grow*1024 + 512 + g*16);
    const unsigned short* pu = (const unsigned short*)&raw;
    alignas(16) unsigned short us[8];
    #pragma unroll
    for (int jx = 0; jx < 8; jx++)
      us[jx] = f2bf(rs * bf2f(pu[jx]) + offvL[g*8 + jx]);
    *(uint4*)(Blds + ((r*512 + g*16) ^ ((r&3)<<4))) = *(uint4*)us;
  }
  __syncthreads();

  float Nf = (float)NN;
  float denv[4][4];
  #pragma unroll
  for (int mt = 0; mt < 4; mt++)
    #pragma unroll
    for (int jj = 0; jj < 4; jj++)
      denv[mt][jj] = Sq * __shfl(accd[mt][jj], lane & 48) + Nf;
  #pragma unroll
  for (int mt = 0; mt < 4; mt++)
    #pragma unroll
    for (int dt = 0; dt < 4; dt++)
      #pragma unroll
      for (int jj = 0; jj < 4; jj++){
        int r = mt*16 + lhi*4 + jj;
        int col = wid*64 + dt*16 + l15;
        long grow = rowbase + r;
        float vv = bf2f(*(const unsigned short*)(Blds + ((r*512 + col*2) ^ ((r&3)<<4))));
        float num = Sq*acc[mt][dt][jj] + Nf*vv;
        if (grow < NN)
          *(float*)(outb + grow*1024 + col*4) = num / denv[mt][jj];
      }
}

extern "C" void kernel_launch(void* const* d_in, const int* in_sizes, int n_in,
                              void* d_out, int out_size, void* d_ws, size_t ws_size,
                              hipStream_t stream) {
  const float* h  = (const float*)d_in[0];
  const float* Wq = (const float*)d_in[1];
  const float* bq = (const float*)d_in[2];
  const float* Wk = (const float*)d_in[3];
  const float* bk = (const float*)d_in[4];
  const float* Wv = (const float*)d_in[5];
  const float* bv = (const float*)d_in[6];
  float* ws = (float*)d_ws;
  char* outb = (char*)d_out;

  hipMemsetAsync(d_ws, 0, WS_WT * sizeof(float), stream);

  k_prep<<<48, 256, 0, stream>>>(Wq, Wk, Wv, ws);
  k_qkv<<<(NN + 63)/64, 256, 49152, stream>>>(h, ws, outb);
  k_kv<<<KVGRID, 256, 57344, stream>>>(outb, ws);
  k_fin<<<1, 256, 0, stream>>>(bq, bk, bv, ws);

  hipFuncSetAttribute(reinterpret_cast<const void*>(k_out),
                      hipFuncAttributeMaxDynamicSharedMemorySize, 68096);
  k_out<<<(NN + 63)/64, 256, 68096, stream>>>(ws, outb);
}

// Round 3
// 120.807 us; speedup vs baseline: 3.8956x; 3.3473x over previous
//
#include <hip/hip_runtime.h>
#include <stdint.h>

#define NN 100000L
#define TRB 2048

// ws float offsets
#define WS_SUMS 0    // [8][2] (sumh, sumh2) spread slots
#define WS_CSW  16   // [256] Wv column sums
#define WS_WT   272  // ushort[256*256] Wv^T bf16 [col][k]

#define AS1 __attribute__((address_space(1)))
#define AS3 __attribute__((address_space(3)))

typedef __attribute__((ext_vector_type(8))) short short8;
typedef __attribute__((ext_vector_type(4))) float f32x4;

__device__ __forceinline__ unsigned short f2bf(float f){
  uint32_t x = __float_as_uint(f);
  x = (x + 0x7FFFu + ((x >> 16) & 1u)) >> 16;
  return (unsigned short)x;
}

// kA: stream h -> stats + bf16 pre-swizzled into out[row][512:1024); plus Wv prep
__global__ __launch_bounds__(256) void kA(const float* __restrict__ h,
    const float* __restrict__ Wv, float* __restrict__ ws, char* __restrict__ outb){
  __shared__ float lds[4096];   // 16KB, both branches use it
  int tid = threadIdx.x;
  if (blockIdx.x < TRB){
    float s = 0.f, s2 = 0.f;
    long gid = (long)blockIdx.x*256 + tid;
    for (long u = gid; u < 3200000L; u += (long)TRB*256){
      long row = u >> 5; int blk = (int)(u & 31);
      const float4* p = (const float4*)(h + row*256 + blk*8);
      float4 a = p[0], b = p[1];
      s  += (a.x+a.y)+(a.z+a.w) + (b.x+b.y)+(b.z+b.w);
      s2 += (a.x*a.x+a.y*a.y)+(a.z*a.z+a.w*a.w)
          + (b.x*b.x+b.y*b.y)+(b.z*b.z+b.w*b.w);
      alignas(16) unsigned short q8[8];
      q8[0]=f2bf(a.x); q8[1]=f2bf(a.y); q8[2]=f2bf(a.z); q8[3]=f2bf(a.w);
      q8[4]=f2bf(b.x); q8[5]=f2bf(b.y); q8[6]=f2bf(b.z); q8[7]=f2bf(b.w);
      // pre-swizzle 16B-unit index by row&7 so kB can global_load_lds linearly
      *(uint4*)(outb + row*1024 + 512 + (long)((blk ^ ((int)row & 7)) << 4)) = *(uint4*)q8;
    }
    #pragma unroll
    for (int o = 32; o; o >>= 1){ s += __shfl_down(s,o); s2 += __shfl_down(s2,o); }
    int w = tid >> 6;
    if ((tid & 63) == 0){ lds[w] = s; lds[4+w] = s2; }
    __syncthreads();
    if (tid == 0)
      atomicAdd(&ws[WS_SUMS + (blockIdx.x & 7)*2 + 0], lds[0]+lds[1]+lds[2]+lds[3]);
    if (tid == 1)
      atomicAdd(&ws[WS_SUMS + (blockIdx.x & 7)*2 + 1], lds[4]+lds[5]+lds[6]+lds[7]);
  } else {
    // Wv^T bf16 + column sums; 16 blocks, one 16-k slab each
    int p = blockIdx.x - TRB;
    int kbase = p*16;
    char* ldsb = (char*)lds;
    #pragma unroll
    for (int i = 0; i < 4; i++){
      int idx = tid + i*256;
      int r = idx >> 6, g = idx & 63;
      float4 v = *(const float4*)(Wv + (kbase + r)*256 + g*4);
      *(float4*)(ldsb + ((r*1024 + g*16) ^ ((r&7)<<4))) = v;
    }
    __syncthreads();
    int j = tid;
    alignas(16) unsigned short us[16];
    float cs = 0.f;
    #pragma unroll
    for (int r = 0; r < 16; r++){
      float f = *(const float*)(ldsb + ((r*1024 + j*4) ^ ((r&7)<<4)));
      cs += f; us[r] = f2bf(f);
    }
    unsigned short* Wt = (unsigned short*)(ws + WS_WT);
    *(uint4*)(Wt + j*256 + kbase)     = *(uint4*)us;
    *(uint4*)(Wt + j*256 + kbase + 8) = *(uint4*)(us + 8);
    atomicAdd(&ws[WS_CSW + j], cs);
  }
}

// kB: per 64-row block: out[rows][256] = rs*(h_bf16 @ Wv_bf16) + offv, fp32 stores.
// Swapped-operand MFMA -> C^T layout -> per-lane 4 consecutive cols -> float4 stores.
__global__ __launch_bounds__(256, 3) void kB(const float* __restrict__ bv,
    const float* __restrict__ ws, char* __restrict__ outb){
  extern __shared__ char Alds[];   // 32KB: [64 rows][512B] bf16, swizzled
  int tid = threadIdx.x, lane = tid & 63, wid = tid >> 6;
  int l15 = lane & 15, lhi = lane >> 4;
  long rowbase = (long)blockIdx.x * 64;
  bool edge = (rowbase + 64 > NN);

  // A stage first (async for non-edge blocks)
  if (!edge){
    #pragma unroll
    for (int i = 0; i < 8; i++){
      int o = (wid*8 + i)*64 + lane;   // 16B-unit index in LDS
      const char* src = outb + (rowbase + (o >> 5))*1024 + 512 + (long)((o & 31) << 4);
      __builtin_amdgcn_global_load_lds((const AS1 uint32_t*)src,
          (AS3 uint32_t*)(Alds + (wid*8 + i)*1024), 16, 0, 0);
    }
  } else {
    #pragma unroll
    for (int i = 0; i < 8; i++){
      int o = tid + i*256;
      long grow = rowbase + (o >> 5);
      uint4 val = {0,0,0,0};
      if (grow < NN) val = *(const uint4*)(outb + grow*1024 + 512 + (long)((o & 31) << 4));
      *(uint4*)(Alds + o*16) = val;
    }
  }

  // LN affine params (local recompute: kills a separate kernel)
  float SUMH = 0.f, SUMH2 = 0.f;
  #pragma unroll
  for (int i = 0; i < 8; i++){ SUMH += ws[WS_SUMS + i*2]; SUMH2 += ws[WS_SUMS + i*2 + 1]; }
  float mu  = SUMH  * (1.0f/25600000.f);
  float var = SUMH2 * (1.0f/25600000.f) - mu*mu;
  float rs  = rsqrtf(var + 1e-5f);
  float4 offc[4];
  #pragma unroll
  for (int nt = 0; nt < 4; nt++){
    int col = wid*64 + nt*16 + lhi*4;
    float4 b4 = *(const float4*)(bv + col);
    float4 c4 = *(const float4*)(ws + WS_CSW + col);
    offc[nt].x = b4.x - mu*rs*c4.x;
    offc[nt].y = b4.y - mu*rs*c4.y;
    offc[nt].z = b4.z - mu*rs*c4.z;
    offc[nt].w = b4.w - mu*rs*c4.w;
  }
  __syncthreads();

  const unsigned short* Wt = (const unsigned short*)(ws + WS_WT);
  f32x4 acc[4][4];
  #pragma unroll
  for (int a = 0; a < 4; a++)
    #pragma unroll
    for (int b = 0; b < 4; b++) acc[a][b] = (f32x4){0.f,0.f,0.f,0.f};

  #pragma unroll
  for (int ks = 0; ks < 8; ks++){
    short8 bf[4], af[4];
    #pragma unroll
    for (int nt = 0; nt < 4; nt++)
      bf[nt] = *(const short8*)(Wt + (wid*64 + nt*16 + l15)*256 + ks*32 + lhi*8);
    #pragma unroll
    for (int mt = 0; mt < 4; mt++){
      int r = mt*16 + l15;
      af[mt] = *(const short8*)(Alds + ((r*512 + ks*64 + lhi*16) ^ ((l15 & 7) << 4)));
    }
    // swapped operands: D = (A@B)^T -> reg jj spans 4 consecutive output cols
    #pragma unroll
    for (int mt = 0; mt < 4; mt++)
      #pragma unroll
      for (int nt = 0; nt < 4; nt++)
        acc[mt][nt] = __builtin_amdgcn_mfma_f32_16x16x32_bf16(bf[nt], af[mt], acc[mt][nt], 0, 0, 0);
  }

  float* outf = (float*)outb;
  #pragma unroll
  for (int mt = 0; mt < 4; mt++){
    long grow = rowbase + mt*16 + l15;    // lane&15 = row in C^T layout
    if (!edge || grow < NN){
      float* rp = outf + grow*256 + wid*64 + lhi*4;
      #pragma unroll
      for (int nt = 0; nt < 4; nt++){
        float4 y;
        y.x = rs*acc[mt][nt][0] + offc[nt].x;
        y.y = rs*acc[mt][nt][1] + offc[nt].y;
        y.z = rs*acc[mt][nt][2] + offc[nt].z;
        y.w = rs*acc[mt][nt][3] + offc[nt].w;
        *(float4*)(rp + nt*16) = y;
      }
    }
  }
}

extern "C" void kernel_launch(void* const* d_in, const int* in_sizes, int n_in,
                              void* d_out, int out_size, void* d_ws, size_t ws_size,
                              hipStream_t stream) {
  const float* h  = (const float*)d_in[0];
  const float* Wv = (const float*)d_in[5];
  const float* bv = (const float*)d_in[6];
  float* ws = (float*)d_ws;
  char* outb = (char*)d_out;

  hipMemsetAsync(d_ws, 0, (WS_WT)*sizeof(float), stream);
  kA<<<TRB + 16, 256, 0, stream>>>(h, Wv, ws, outb);
  kB<<<(int)((NN + 63)/64), 256, 32768, stream>>>(bv, ws, outb);
}